// Round 13
// baseline (188.835 us; speedup 1.0000x reference)
//
#include <hip/hip_runtime.h>
#include <stdint.h>

// Problem constants (from reference)
#define NGRAPH 1024
#define DFEAT  256     // D
#define KATOM  64      // atoms per graph
#define KBOND  128     // bonds per graph

typedef __attribute__((ext_vector_type(4))) float accv_t;     // MFMA C/D (4 fp32)
typedef __attribute__((ext_vector_type(8))) short bfrag_t;    // MFMA A/B (8 bf16)
typedef __attribute__((ext_vector_type(4))) unsigned short upk4_t;
typedef __attribute__((ext_vector_type(8))) unsigned short upk8_t;
typedef __attribute__((ext_vector_type(4))) unsigned int u32x4;

__device__ __forceinline__ unsigned short f2bf(float f) {
    union { float f; unsigned int u; } v; v.f = f;
    return (unsigned short)((v.u + 0x7FFFu + ((v.u >> 16) & 1u)) >> 16);
}
__device__ __forceinline__ float bf2f(unsigned short h) {
    union { unsigned int u; float f; } v; v.u = ((unsigned int)h) << 16;
    return v.f;
}
__device__ __forceinline__ float sigm(float x) { return 1.0f / (1.0f + __expf(-x)); }
__device__ __forceinline__ float tanh_f(float x) {
    float e = __expf(2.0f * x);
    return 1.0f - 2.0f / (e + 1.0f);
}
__device__ __forceinline__ unsigned int packq(float a, float b, float c, float d, float inv) {
    int q0 = (int)rintf(a * inv), q1 = (int)rintf(b * inv);
    int q2 = (int)rintf(c * inv), q3 = (int)rintf(d * inv);
    return (unsigned int)(q0 & 0xFF) | ((unsigned int)(q1 & 0xFF) << 8)
         | ((unsigned int)(q2 & 0xFF) << 16) | ((unsigned int)(q3 & 0xFF) << 24);
}
__device__ __forceinline__ void dec16(const unsigned int* h, float* x) {
    #pragma unroll
    for (int w4 = 0; w4 < 4; ++w4) {
        unsigned int u = h[w4];
        x[w4 * 4 + 0] = (float)((int)(u << 24) >> 24);
        x[w4 * 4 + 1] = (float)((int)(u << 16) >> 24);
        x[w4 * 4 + 2] = (float)((int)(u << 8)  >> 24);
        x[w4 * 4 + 3] = (float)((int)u >> 24);
    }
}

// ---------------------------------------------------------------------------
// Fused prologue. Blocks 0..1023: fp32 -> int8 quantization of both feature
// arrays (per-node per-32-dim-block scales; NT source loads). Blocks
// 1024..3071: Wc prep in GATE-INTERLEAVED row order so the GEMM epilogue has
// all 4 gates of a dim in one lane: newrow(g,d) = (d>>4)*64 + g*16 + (d&15).
// bsum stays gate-major.
// ---------------------------------------------------------------------------
__global__ __launch_bounds__(256) void k_cvtprep(
    const float* __restrict__ fA, const float* __restrict__ fB,
    unsigned int* __restrict__ oA, unsigned int* __restrict__ oB,
    float* __restrict__ scA, float* __restrict__ scB,
    const float* __restrict__ WihA, const float* __restrict__ WhhA,
    const float* __restrict__ bihA, const float* __restrict__ bhhA,
    const float* __restrict__ WihB, const float* __restrict__ WhhB,
    const float* __restrict__ bihB, const float* __restrict__ bhhB,
    unsigned short* __restrict__ Wc, float* __restrict__ bsum, int doquant)
{
    int bid = blockIdx.x;
    if (bid < 1024) {
        if (!doquant) return;
        int wid  = bid * 4 + (threadIdx.x >> 6);   // 0..4095
        int lane = threadIdx.x & 63;
        int grp  = lane >> 3;
        #pragma unroll 2
        for (int n = wid; n < 65536; n += 4096) {
            accv_t v = __builtin_nontemporal_load((const accv_t*)(fA + (size_t)n * 256) + lane);
            float m = fmaxf(fmaxf(fabsf(v[0]), fabsf(v[1])), fmaxf(fabsf(v[2]), fabsf(v[3])));
            m = fmaxf(m, __shfl_xor(m, 1));
            m = fmaxf(m, __shfl_xor(m, 2));
            m = fmaxf(m, __shfl_xor(m, 4));
            float inv = (m > 0.0f) ? 127.0f / m : 0.0f;
            oA[(size_t)n * 64 + lane] = packq(v[0], v[1], v[2], v[3], inv);
            if ((lane & 7) == 0) scA[(size_t)n * 8 + grp] = m * (1.0f / 127.0f);
        }
        #pragma unroll 2
        for (int n = wid; n < 131072; n += 4096) {
            accv_t v = __builtin_nontemporal_load((const accv_t*)(fB + (size_t)n * 256) + lane);
            float m = fmaxf(fmaxf(fabsf(v[0]), fabsf(v[1])), fmaxf(fabsf(v[2]), fabsf(v[3])));
            m = fmaxf(m, __shfl_xor(m, 1));
            m = fmaxf(m, __shfl_xor(m, 2));
            m = fmaxf(m, __shfl_xor(m, 4));
            float inv = (m > 0.0f) ? 127.0f / m : 0.0f;
            oB[(size_t)n * 64 + lane] = packq(v[0], v[1], v[2], v[3], inv);
            if ((lane & 7) == 0) scB[(size_t)n * 8 + grp] = m * (1.0f / 127.0f);
        }
    } else {
        int pid = bid - 1024;
        int set = pid >> 10;
        int n   = pid & 1023;                      // orig gate-major row
        int g0  = n >> 8;
        int d0  = n & 255;
        int nr  = ((d0 >> 4) << 6) + (g0 << 4) + (d0 & 15);   // gate-interleaved
        int k   = threadIdx.x;                     // 0..255
        const float* Wih = set ? WihB : WihA;
        const float* Whh = set ? WhhB : WhhA;
        float w1 = Wih[(size_t)n * 512 + k] + Whh[(size_t)n * 256 + k];
        float w2 = Wih[(size_t)n * 512 + 256 + k];
        size_t base = ((size_t)(set << 10) + nr) * 512;
        Wc[base + k]       = f2bf(w1);
        Wc[base + 256 + k] = f2bf(w2);
        if (k == 0) {
            const float* bih = set ? bihB : bihA;
            const float* bhh = set ? bhhB : bhhA;
            bsum[(set << 10) + n] = bih[n] + bhh[n];
        }
    }
}

// ---------------------------------------------------------------------------
// Fused GEMM + LSTM: raw = hprev_bf @ Wc^T (gate-interleaved cols), then the
// epilogue applies bias + LSTM per (graph, dim) IN-LANE (each lane's 4 acc
// j-fragments = i,f,g,o of one dim x 4 graphs) and writes h (bf16) into the
// q-half of hcur, updating cst. No gates buffer. hprev/hcur are double
// buffers (avoids WAR on the q-half). LAST: h also written to out (f32).
// M=1024, N=1024(interleaved), K=512 per set. BM=64, BN=64, 4 waves of
// 16x64 (acc[4]). grid: 512 blocks (set = bid>>8).
// ---------------------------------------------------------------------------
template <bool LAST>
__global__ __launch_bounds__(256) void k_gemm(
    const unsigned short* __restrict__ hprev, const unsigned short* __restrict__ Wc,
    const float* __restrict__ bsum, float* __restrict__ cst,
    unsigned short* __restrict__ hcur, float* __restrict__ outp)
{
    __shared__ unsigned short sA[64 * 40];
    __shared__ unsigned short sB[64 * 40];

    int set   = blockIdx.x >> 8;
    int qq    = blockIdx.x & 255;
    int mbase = (qq >> 4) * 64;
    int nbase = (qq & 15) * 64;
    int t     = threadIdx.x;
    int lane  = t & 63;
    int w     = t >> 6;
    int wrow  = w << 4;              // 16 rows per wave
    int l15   = lane & 15;
    int khalf = (lane >> 4) * 8;

    const unsigned short* Am = hprev + (size_t)(set << 10) * 512;
    const unsigned short* Bm = Wc    + (size_t)(set << 10) * 512;

    accv_t acc[4];
    #pragma unroll
    for (int j = 0; j < 4; ++j) acc[j] = (accv_t){0.f, 0.f, 0.f, 0.f};

    int srow = t >> 2;
    int skc  = (t & 3) * 8;
    for (int k0 = 0; k0 < 512; k0 += 32) {
        *(upk8_t*)&sA[srow * 40 + skc] =
            *(const upk8_t*)&Am[(size_t)(mbase + srow) * 512 + k0 + skc];
        *(upk8_t*)&sB[srow * 40 + skc] =
            *(const upk8_t*)&Bm[(size_t)(nbase + srow) * 512 + k0 + skc];
        __syncthreads();

        bfrag_t a_f = *(const bfrag_t*)&sA[(wrow + l15) * 40 + khalf];
        bfrag_t b_f[4];
        #pragma unroll
        for (int j = 0; j < 4; ++j)
            b_f[j] = *(const bfrag_t*)&sB[(j * 16 + l15) * 40 + khalf];
        #pragma unroll
        for (int j = 0; j < 4; ++j)
            acc[j] = __builtin_amdgcn_mfma_f32_16x16x32_bf16(a_f, b_f[j], acc[j], 0, 0, 0);
        __syncthreads();
    }

    // epilogue: acc[j][v] = gate j for dim d, graph (mbase+wrow+r4+v)
    int r4   = (lane >> 4) * 4;
    int d    = (nbase >> 2) + l15;   // dim 0..255
    int sb10 = set << 10;
    float bi = bsum[sb10 + d];
    float bf_ = bsum[sb10 + 256 + d];
    float bg = bsum[sb10 + 512 + d];
    float bo = bsum[sb10 + 768 + d];
    #pragma unroll
    for (int v = 0; v < 4; ++v) {
        int graph  = mbase + wrow + r4 + v;
        size_t gi_ = (size_t)sb10 + graph;
        float cold = cst[gi_ * 256 + d];
        float xi = acc[0][v] + bi;
        float xf = acc[1][v] + bf_;
        float xg = acc[2][v] + bg;
        float xo = acc[3][v] + bo;
        float cn = sigm(xf) * cold + sigm(xi) * tanh_f(xg);
        float h  = sigm(xo) * tanh_f(cn);
        if (!LAST) cst[gi_ * 256 + d] = cn;
        hcur[gi_ * 512 + d] = f2bf(h);
        if (LAST) outp[(size_t)graph * 1152 + (set ? 512 : 0) + d] = h;
    }
}

// ---------------------------------------------------------------------------
// Attention, templated on MODE / LAST:
//  MODE 1: int8 copy + per-32-dim-block scales; MODE 2: fp32 fallback.
// iter==0: bias-only LSTM computed here (writes cst + q-half of hrcur).
// iter>=1: q loaded from hrcur (written by the fused GEMM+LSTM).
// Writes r-half of hrcur; LAST writes r (+feat_global tail) to out.
// grid: 2048 blocks (0..1023 bonds, 1024..2047 atoms), 256 threads.
// ---------------------------------------------------------------------------
template <int MODE, bool LAST>
__global__ __launch_bounds__(256) void k_attn(
    const float* __restrict__ featA, const float* __restrict__ featB,
    const unsigned int* __restrict__ i8A, const unsigned int* __restrict__ i8B,
    const float* __restrict__ scA, const float* __restrict__ scB,
    const float* __restrict__ bsum, unsigned short* __restrict__ hrcur,
    float* __restrict__ cst, const float* __restrict__ fgp,
    float* __restrict__ outp, int iter)
{
    __shared__ float qv[256];
    __shared__ float sw_s[16], cw_s[16];
    __shared__ float racc_s[16][260];

    int bid = blockIdx.x;
    int set = (bid < 1024) ? 1 : 0;          // bonds first (2x work)
    int b   = bid & 1023;
    int K   = set ? KBOND : KATOM;
    int t = threadIdx.x;
    size_t sb = (size_t)(set << 10) + b;
    size_t ob = (size_t)b * 1152 + (set ? 512 : 0);

    // ---- stage 1: q into qv (iter0: bias LSTM; else load from hrcur) ----
    {
        int d = t;
        if (iter == 0) {
            float gi = bsum[(set << 10) + d];
            float gf = bsum[(set << 10) + 256 + d];
            float gg = bsum[(set << 10) + 512 + d];
            float go = bsum[(set << 10) + 768 + d];
            float cn = sigm(gi) * tanh_f(gg);        // cold = 0
            float h  = sigm(go) * tanh_f(cn);
            cst[sb * 256 + d]   = cn;
            hrcur[sb * 512 + d] = f2bf(h);
            qv[d] = h;
        } else {
            qv[d] = bf2f(hrcur[sb * 512 + d]);
        }
    }
    __syncthreads();

    int lane = t & 63;
    int wv   = t >> 6;
    int g    = lane >> 4;
    int s    = lane & 15;
    int npw  = K >> 2;
    int nq   = npw >> 2;
    int node0 = wv * npw + g;
    float C = 0.0f, sacc = 0.0f;
    int pid = (wv << 2) | g;

    if (MODE == 1) {
        // int8 read path: per node 1 uint4 (16 int8, dims 16s..16s+16) + scale
        const unsigned int* fb = (set ? i8B : i8A)
                               + ((size_t)b * K + node0) * 64 + s * 4;
        const float* scp = (set ? scB : scA)
                         + ((size_t)b * K + node0) * 8 + (s >> 1);

        float qr[16];
        #pragma unroll
        for (int j = 0; j < 16; ++j) qr[j] = qv[s * 16 + j];
        float r[16];
        #pragma unroll
        for (int j = 0; j < 16; ++j) r[j] = 0.0f;

        #pragma unroll 4
        for (int qd = 0; qd < nq; ++qd) {
            u32x4 hx = *(const u32x4*)(fb + (size_t)qd * 256);
            float sc = scp[(size_t)qd * 32];
            float x[16];
            dec16((const unsigned int*)&hx, x);
            float e = 0.0f;
            #pragma unroll
            for (int j = 0; j < 16; ++j) e += x[j] * qr[j];
            e *= sc;
            e += __shfl_xor(e, 1);
            e += __shfl_xor(e, 2);
            e += __shfl_xor(e, 4);
            e += __shfl_xor(e, 8);
            float w = (qd == 0) ? 1.0f : __expf(e - C);
            if (qd == 0) C = e;
            sacc += w;
            float wl = w * sc;
            #pragma unroll
            for (int j = 0; j < 16; ++j) r[j] += wl * x[j];
        }
        #pragma unroll
        for (int j = 0; j < 16; j += 4)
            *(float4*)&racc_s[pid][s * 16 + j] = *(float4*)&r[j];
    } else {
        // fp32 fallback: lane owns dims {c*64 + s*4..+4}, c=0..3
        const float* feat = set ? featB : featA;
        const float* fb = feat + ((size_t)b * K + node0) * 256 + s * 4;
        float4 q0 = *(const float4*)&qv[s*4];
        float4 q1 = *(const float4*)&qv[64  + s*4];
        float4 q2 = *(const float4*)&qv[128 + s*4];
        float4 q3 = *(const float4*)&qv[192 + s*4];
        float4 r0 = make_float4(0.f,0.f,0.f,0.f), r1 = r0, r2 = r0, r3 = r0;
        #pragma unroll 2
        for (int qd = 0; qd < nq; ++qd) {
            const float* p = fb + (size_t)qd * 1024;
            float4 x0 = *(const float4*)(p);
            float4 x1 = *(const float4*)(p + 64);
            float4 x2 = *(const float4*)(p + 128);
            float4 x3 = *(const float4*)(p + 192);
            float e = x0.x*q0.x + x0.y*q0.y + x0.z*q0.z + x0.w*q0.w
                    + x1.x*q1.x + x1.y*q1.y + x1.z*q1.z + x1.w*q1.w
                    + x2.x*q2.x + x2.y*q2.y + x2.z*q2.z + x2.w*q2.w
                    + x3.x*q3.x + x3.y*q3.y + x3.z*q3.z + x3.w*q3.w;
            e += __shfl_xor(e, 1); e += __shfl_xor(e, 2);
            e += __shfl_xor(e, 4); e += __shfl_xor(e, 8);
            float w = (qd == 0) ? 1.0f : __expf(e - C);
            if (qd == 0) C = e;
            sacc += w;
            r0.x += w*x0.x; r0.y += w*x0.y; r0.z += w*x0.z; r0.w += w*x0.w;
            r1.x += w*x1.x; r1.y += w*x1.y; r1.z += w*x1.z; r1.w += w*x1.w;
            r2.x += w*x2.x; r2.y += w*x2.y; r2.z += w*x2.z; r2.w += w*x2.w;
            r3.x += w*x3.x; r3.y += w*x3.y; r3.z += w*x3.z; r3.w += w*x3.w;
        }
        *(float4*)&racc_s[pid][s*4]       = r0;
        *(float4*)&racc_s[pid][64  + s*4] = r1;
        *(float4*)&racc_s[pid][128 + s*4] = r2;
        *(float4*)&racc_s[pid][192 + s*4] = r3;
    }
    if (s == 0) { sw_s[pid] = sacc; cw_s[pid] = C; }
    __syncthreads();

    // ---- stage 3: pivot-reconciled merge of 16 partials, d = t ----
    {
        float Cm = cw_s[0];
        #pragma unroll
        for (int p2 = 1; p2 < 16; ++p2) Cm = fmaxf(Cm, cw_s[p2]);
        float S = 0.0f, r = 0.0f;
        #pragma unroll
        for (int p2 = 0; p2 < 16; ++p2) {
            float f = __expf(cw_s[p2] - Cm);
            S += sw_s[p2] * f;
            r += racc_s[p2][t] * f;
        }
        float rv = r / S;
        if (LAST) {
            outp[ob + 256 + t] = rv;
            if (set && t < 128)
                outp[(size_t)b * 1152 + 1024 + t] = fgp[(size_t)b * 128 + t];
        } else {
            hrcur[sb * 512 + 256 + t] = f2bf(rv);
        }
    }
}

extern "C" void kernel_launch(void* const* d_in, const int* in_sizes, int n_in,
                              void* d_out, int out_size, void* d_ws, size_t ws_size,
                              hipStream_t stream) {
    const float* feat_atom   = (const float*)d_in[0];
    const float* feat_bond   = (const float*)d_in[2];
    const float* feat_global = (const float*)d_in[4];
    const float* WihA = (const float*)d_in[5];
    const float* WhhA = (const float*)d_in[6];
    const float* bihA = (const float*)d_in[7];
    const float* bhhA = (const float*)d_in[8];
    const float* WihB = (const float*)d_in[9];
    const float* WhhB = (const float*)d_in[10];
    const float* bihB = (const float*)d_in[11];
    const float* bhhB = (const float*)d_in[12];
    float* out = (float*)d_out;

    // workspace layout (bytes)
    char* ws = (char*)d_ws;
    unsigned short* Wc   = (unsigned short*)(ws + 0);         // 2,097,152
    float*          bsum = (float*)(ws + 2097152);            // 8,192
    float*          cst  = (float*)(ws + 2105344);            // 2,097,152
    unsigned short* hrb0 = (unsigned short*)(ws + 4202496);   // 2,097,152 (bf16)
    unsigned short* hrb1 = (unsigned short*)(ws + 6299648);   // 2,097,152 (bf16)
    unsigned int*   i8A  = (unsigned int*)(ws + 8396800);     // 16,777,216
    unsigned int*   i8B  = (unsigned int*)(ws + 25174016);    // 33,554,432
    float*          scA  = (float*)(ws + 58728448);           // 2,097,152
    float*          scB  = (float*)(ws + 60825600);           // 4,194,304
    const size_t WS_NEED = 60825600 + 4194304;                // 65,019,904
    (void)in_sizes; (void)n_in; (void)out_size;

    bool i8 = (ws_size >= WS_NEED);

    k_cvtprep<<<3072, 256, 0, stream>>>(feat_atom, feat_bond, i8A, i8B, scA, scB,
                                        WihA, WhhA, bihA, bhhA,
                                        WihB, WhhB, bihB, bhhB,
                                        Wc, bsum, i8 ? 1 : 0);
    if (i8) {
        k_attn<1, false><<<2048, 256, 0, stream>>>(feat_atom, feat_bond, i8A, i8B,
                                                   scA, scB, bsum, hrb0, cst,
                                                   feat_global, out, 0);
        for (int it = 1; it < 5; ++it) {
            unsigned short* prev = (it & 1) ? hrb0 : hrb1;
            unsigned short* cur  = (it & 1) ? hrb1 : hrb0;
            k_gemm<false><<<512, 256, 0, stream>>>(prev, Wc, bsum, cst, cur, out);
            k_attn<1, false><<<2048, 256, 0, stream>>>(feat_atom, feat_bond, i8A, i8B,
                                                       scA, scB, bsum, cur, cst,
                                                       feat_global, out, it);
        }
        k_gemm<true><<<512, 256, 0, stream>>>(hrb0, Wc, bsum, cst, hrb1, out);
        k_attn<1, true><<<2048, 256, 0, stream>>>(feat_atom, feat_bond, i8A, i8B,
                                                  scA, scB, bsum, hrb1, cst,
                                                  feat_global, out, 5);
    } else {
        k_attn<2, false><<<2048, 256, 0, stream>>>(feat_atom, feat_bond, 0, 0, 0, 0,
                                                   bsum, hrb0, cst,
                                                   feat_global, out, 0);
        for (int it = 1; it < 5; ++it) {
            unsigned short* prev = (it & 1) ? hrb0 : hrb1;
            unsigned short* cur  = (it & 1) ? hrb1 : hrb0;
            k_gemm<false><<<512, 256, 0, stream>>>(prev, Wc, bsum, cst, cur, out);
            k_attn<2, false><<<2048, 256, 0, stream>>>(feat_atom, feat_bond, 0, 0, 0, 0,
                                                       bsum, cur, cst,
                                                       feat_global, out, it);
        }
        k_gemm<true><<<512, 256, 0, stream>>>(hrb0, Wc, bsum, cst, hrb1, out);
        k_attn<2, true><<<2048, 256, 0, stream>>>(feat_atom, feat_bond, 0, 0, 0, 0,
                                                  bsum, hrb1, cst,
                                                  feat_global, out, 5);
    }
}

// Round 14
// 186.317 us; speedup vs baseline: 1.0135x; 1.0135x over previous
//
#include <hip/hip_runtime.h>
#include <stdint.h>

// Problem constants (from reference)
#define NGRAPH 1024
#define DFEAT  256     // D
#define KATOM  64      // atoms per graph
#define KBOND  128     // bonds per graph

typedef __attribute__((ext_vector_type(4))) float accv_t;     // MFMA C/D (4 fp32)
typedef __attribute__((ext_vector_type(8))) short bfrag_t;    // MFMA A/B (8 bf16)
typedef __attribute__((ext_vector_type(4))) unsigned short upk4_t;
typedef __attribute__((ext_vector_type(8))) unsigned short upk8_t;
typedef __attribute__((ext_vector_type(4))) unsigned int u32x4;

__device__ __forceinline__ unsigned short f2bf(float f) {
    union { float f; unsigned int u; } v; v.f = f;
    return (unsigned short)((v.u + 0x7FFFu + ((v.u >> 16) & 1u)) >> 16);
}
__device__ __forceinline__ float bf2f(unsigned short h) {
    union { unsigned int u; float f; } v; v.u = ((unsigned int)h) << 16;
    return v.f;
}
__device__ __forceinline__ float sigm(float x) { return 1.0f / (1.0f + __expf(-x)); }
__device__ __forceinline__ float tanh_f(float x) {
    float e = __expf(2.0f * x);
    return 1.0f - 2.0f / (e + 1.0f);
}
__device__ __forceinline__ unsigned int packq(float a, float b, float c, float d, float inv) {
    int q0 = (int)rintf(a * inv), q1 = (int)rintf(b * inv);
    int q2 = (int)rintf(c * inv), q3 = (int)rintf(d * inv);
    return (unsigned int)(q0 & 0xFF) | ((unsigned int)(q1 & 0xFF) << 8)
         | ((unsigned int)(q2 & 0xFF) << 16) | ((unsigned int)(q3 & 0xFF) << 24);
}
__device__ __forceinline__ void dec16(const unsigned int* h, float* x) {
    #pragma unroll
    for (int w4 = 0; w4 < 4; ++w4) {
        unsigned int u = h[w4];
        x[w4 * 4 + 0] = (float)((int)(u << 24) >> 24);
        x[w4 * 4 + 1] = (float)((int)(u << 16) >> 24);
        x[w4 * 4 + 2] = (float)((int)(u << 8)  >> 24);
        x[w4 * 4 + 3] = (float)((int)u >> 24);
    }
}

// ---------------------------------------------------------------------------
// Fused prologue. Blocks 0..1023: streaming fp32 -> int8 quantization of both
// feature arrays (per-node per-32-dim-block scales; NT loads keep fp32 out of
// L3). Blocks 1024..3071: Wc prep (bf16) and bsum = b_ih + b_hh.
// ---------------------------------------------------------------------------
__global__ __launch_bounds__(256) void k_cvtprep(
    const float* __restrict__ fA, const float* __restrict__ fB,
    unsigned int* __restrict__ oA, unsigned int* __restrict__ oB,
    float* __restrict__ scA, float* __restrict__ scB,
    const float* __restrict__ WihA, const float* __restrict__ WhhA,
    const float* __restrict__ bihA, const float* __restrict__ bhhA,
    const float* __restrict__ WihB, const float* __restrict__ WhhB,
    const float* __restrict__ bihB, const float* __restrict__ bhhB,
    unsigned short* __restrict__ Wc, float* __restrict__ bsum, int doquant)
{
    int bid = blockIdx.x;
    if (bid < 1024) {
        if (!doquant) return;
        int wid  = bid * 4 + (threadIdx.x >> 6);   // 0..4095
        int lane = threadIdx.x & 63;
        int grp  = lane >> 3;
        #pragma unroll 2
        for (int n = wid; n < 65536; n += 4096) {
            accv_t v = __builtin_nontemporal_load((const accv_t*)(fA + (size_t)n * 256) + lane);
            float m = fmaxf(fmaxf(fabsf(v[0]), fabsf(v[1])), fmaxf(fabsf(v[2]), fabsf(v[3])));
            m = fmaxf(m, __shfl_xor(m, 1));
            m = fmaxf(m, __shfl_xor(m, 2));
            m = fmaxf(m, __shfl_xor(m, 4));
            float inv = (m > 0.0f) ? 127.0f / m : 0.0f;
            oA[(size_t)n * 64 + lane] = packq(v[0], v[1], v[2], v[3], inv);
            if ((lane & 7) == 0) scA[(size_t)n * 8 + grp] = m * (1.0f / 127.0f);
        }
        #pragma unroll 2
        for (int n = wid; n < 131072; n += 4096) {
            accv_t v = __builtin_nontemporal_load((const accv_t*)(fB + (size_t)n * 256) + lane);
            float m = fmaxf(fmaxf(fabsf(v[0]), fabsf(v[1])), fmaxf(fabsf(v[2]), fabsf(v[3])));
            m = fmaxf(m, __shfl_xor(m, 1));
            m = fmaxf(m, __shfl_xor(m, 2));
            m = fmaxf(m, __shfl_xor(m, 4));
            float inv = (m > 0.0f) ? 127.0f / m : 0.0f;
            oB[(size_t)n * 64 + lane] = packq(v[0], v[1], v[2], v[3], inv);
            if ((lane & 7) == 0) scB[(size_t)n * 8 + grp] = m * (1.0f / 127.0f);
        }
    } else {
        int pid = bid - 1024;
        int set = pid >> 10;
        int n   = pid & 1023;
        int k   = threadIdx.x;                     // 0..255
        const float* Wih = set ? WihB : WihA;
        const float* Whh = set ? WhhB : WhhA;
        float w1 = Wih[(size_t)n * 512 + k] + Whh[(size_t)n * 256 + k];
        float w2 = Wih[(size_t)n * 512 + 256 + k];
        size_t base = ((size_t)(set << 10) + n) * 512;
        Wc[base + k]       = f2bf(w1);
        Wc[base + 256 + k] = f2bf(w2);
        if (k == 0) {
            const float* bih = set ? bihB : bihA;
            const float* bhh = set ? bhhB : bhhA;
            bsum[(set << 10) + n] = bih[n] + bhh[n];
        }
    }
}

// ---------------------------------------------------------------------------
// LSTM gate GEMM: gates_bf[set][m][n] (bf16) = hr_bf @ Wc^T + bsum.
// M=1024, N=1024, K=512 per set. BM=64, BN=64, BK=32, 4 waves (32x32 each),
// 16x16x32 bf16 MFMA. grid: 512 blocks (set = bid>>8) -> 2 blocks/CU.
// ---------------------------------------------------------------------------
__global__ __launch_bounds__(256) void k_gemm(
    const unsigned short* __restrict__ hrb, const unsigned short* __restrict__ Wc,
    const float* __restrict__ bsum, unsigned short* __restrict__ gates)
{
    __shared__ unsigned short sA[64 * 40];
    __shared__ unsigned short sB[64 * 40];

    int set   = blockIdx.x >> 8;
    int qq    = blockIdx.x & 255;
    int mbase = (qq >> 4) * 64;
    int nbase = (qq & 15) * 64;
    int t     = threadIdx.x;
    int lane  = t & 63;
    int w     = t >> 6;
    int wrow  = (w >> 1) * 32;
    int wcol  = (w & 1) * 32;
    int l15   = lane & 15;
    int khalf = (lane >> 4) * 8;

    const unsigned short* Am = hrb + (size_t)(set << 10) * 512;
    const unsigned short* Bm = Wc  + (size_t)(set << 10) * 512;

    accv_t acc[2][2];
    #pragma unroll
    for (int i = 0; i < 2; ++i)
        #pragma unroll
        for (int j = 0; j < 2; ++j)
            acc[i][j] = (accv_t){0.f, 0.f, 0.f, 0.f};

    int srow = t >> 2;
    int skc  = (t & 3) * 8;
    for (int k0 = 0; k0 < 512; k0 += 32) {
        *(upk8_t*)&sA[srow * 40 + skc] =
            *(const upk8_t*)&Am[(size_t)(mbase + srow) * 512 + k0 + skc];
        *(upk8_t*)&sB[srow * 40 + skc] =
            *(const upk8_t*)&Bm[(size_t)(nbase + srow) * 512 + k0 + skc];
        __syncthreads();

        bfrag_t a_f[2], b_f[2];
        #pragma unroll
        for (int i = 0; i < 2; ++i)
            a_f[i] = *(const bfrag_t*)&sA[(wrow + i * 16 + l15) * 40 + khalf];
        #pragma unroll
        for (int j = 0; j < 2; ++j)
            b_f[j] = *(const bfrag_t*)&sB[(wcol + j * 16 + l15) * 40 + khalf];
        #pragma unroll
        for (int i = 0; i < 2; ++i)
            #pragma unroll
            for (int j = 0; j < 2; ++j)
                acc[i][j] = __builtin_amdgcn_mfma_f32_16x16x32_bf16(a_f[i], b_f[j], acc[i][j], 0, 0, 0);
        __syncthreads();
    }

    int r4 = (lane >> 4) * 4;
    #pragma unroll
    for (int i = 0; i < 2; ++i) {
        #pragma unroll
        for (int j = 0; j < 2; ++j) {
            int col  = nbase + wcol + j * 16 + l15;
            float bs = bsum[(set << 10) + col];
            #pragma unroll
            for (int v = 0; v < 2; ++v) {
                int row0 = mbase + wrow + i * 16 + r4 + 2 * v;
                gates[((size_t)(set << 10) + row0) * 1024 + col]     = f2bf(acc[i][j][2 * v] + bs);
                gates[((size_t)(set << 10) + row0 + 1) * 1024 + col] = f2bf(acc[i][j][2 * v + 1] + bs);
            }
        }
    }
}

// ---------------------------------------------------------------------------
// Attention, templated on MODE / LAST:
//  MODE 1: read int8 copy + per-32-dim-block scales; MODE 2: fp32 fallback.
//  LAST: write q_star (and feat_global tail) straight to out (f32).
// gates read bf16; hr written bf16 (only consumed by the bf16 GEMM, so
// numerically identical to f32-hr + in-gemm f2bf).
// grid: 2048 blocks (0..1023 bonds, 1024..2047 atoms), 256 threads.
// ---------------------------------------------------------------------------
template <int MODE, bool LAST>
__global__ __launch_bounds__(256) void k_attn(
    const float* __restrict__ featA, const float* __restrict__ featB,
    const unsigned int* __restrict__ i8A, const unsigned int* __restrict__ i8B,
    const float* __restrict__ scA, const float* __restrict__ scB,
    const unsigned short* __restrict__ gates, const float* __restrict__ bsum,
    unsigned short* __restrict__ hrb, float* __restrict__ cst,
    const float* __restrict__ fgp, float* __restrict__ outp, int iter)
{
    __shared__ float qv[256];
    __shared__ float sw_s[16], cw_s[16];
    __shared__ float racc_s[16][260];

    int bid = blockIdx.x;
    int set = (bid < 1024) ? 1 : 0;          // bonds first (2x work)
    int b   = bid & 1023;
    int K   = set ? KBOND : KATOM;
    int t = threadIdx.x;
    size_t sb = (size_t)(set << 10) + b;
    size_t ob = (size_t)b * 1152 + (set ? 512 : 0);

    // ---- stage 1: LSTM elementwise, d = t ----
    {
        int d = t;
        float gi, gf, gg, go, cold;
        if (iter == 0) {
            gi = bsum[(set << 10) + d];
            gf = bsum[(set << 10) + 256 + d];
            gg = bsum[(set << 10) + 512 + d];
            go = bsum[(set << 10) + 768 + d];
            cold = 0.0f;
        } else {
            const unsigned short* gp = gates + sb * 1024;
            gi = bf2f(gp[d]); gf = bf2f(gp[256 + d]);
            gg = bf2f(gp[512 + d]); go = bf2f(gp[768 + d]);
            cold = cst[sb * 256 + d];
        }
        float cn = sigm(gf) * cold + sigm(gi) * tanh_f(gg);
        float h  = sigm(go) * tanh_f(cn);
        if (LAST) { outp[ob + d] = h; }
        else      { cst[sb * 256 + d] = cn; hrb[sb * 512 + d] = f2bf(h); }
        qv[d] = h;
    }
    __syncthreads();

    int lane = t & 63;
    int wv   = t >> 6;
    int g    = lane >> 4;
    int s    = lane & 15;
    int npw  = K >> 2;
    int nq   = npw >> 2;
    int node0 = wv * npw + g;
    float C = 0.0f, sacc = 0.0f;
    int pid = (wv << 2) | g;

    if (MODE == 1) {
        // int8 read path: per node 1 uint4 (16 int8, dims 16s..16s+16) + scale
        const unsigned int* fb = (set ? i8B : i8A)
                               + ((size_t)b * K + node0) * 64 + s * 4;
        const float* scp = (set ? scB : scA)
                         + ((size_t)b * K + node0) * 8 + (s >> 1);

        float qr[16];
        #pragma unroll
        for (int j = 0; j < 16; ++j) qr[j] = qv[s * 16 + j];
        float r[16];
        #pragma unroll
        for (int j = 0; j < 16; ++j) r[j] = 0.0f;

        #pragma unroll 4
        for (int qd = 0; qd < nq; ++qd) {
            u32x4 hx = *(const u32x4*)(fb + (size_t)qd * 256);
            float sc = scp[(size_t)qd * 32];
            float x[16];
            dec16((const unsigned int*)&hx, x);
            float e = 0.0f;
            #pragma unroll
            for (int j = 0; j < 16; ++j) e += x[j] * qr[j];
            e *= sc;
            e += __shfl_xor(e, 1);
            e += __shfl_xor(e, 2);
            e += __shfl_xor(e, 4);
            e += __shfl_xor(e, 8);
            float w = (qd == 0) ? 1.0f : __expf(e - C);
            if (qd == 0) C = e;
            sacc += w;
            float wl = w * sc;
            #pragma unroll
            for (int j = 0; j < 16; ++j) r[j] += wl * x[j];
        }
        #pragma unroll
        for (int j = 0; j < 16; j += 4)
            *(float4*)&racc_s[pid][s * 16 + j] = *(float4*)&r[j];
    } else {
        // fp32 fallback: lane owns dims {c*64 + s*4..+4}, c=0..3
        const float* feat = set ? featB : featA;
        const float* fb = feat + ((size_t)b * K + node0) * 256 + s * 4;
        float4 q0 = *(const float4*)&qv[s*4];
        float4 q1 = *(const float4*)&qv[64  + s*4];
        float4 q2 = *(const float4*)&qv[128 + s*4];
        float4 q3 = *(const float4*)&qv[192 + s*4];
        float4 r0 = make_float4(0.f,0.f,0.f,0.f), r1 = r0, r2 = r0, r3 = r0;
        #pragma unroll 2
        for (int qd = 0; qd < nq; ++qd) {
            const float* p = fb + (size_t)qd * 1024;
            float4 x0 = *(const float4*)(p);
            float4 x1 = *(const float4*)(p + 64);
            float4 x2 = *(const float4*)(p + 128);
            float4 x3 = *(const float4*)(p + 192);
            float e = x0.x*q0.x + x0.y*q0.y + x0.z*q0.z + x0.w*q0.w
                    + x1.x*q1.x + x1.y*q1.y + x1.z*q1.z + x1.w*q1.w
                    + x2.x*q2.x + x2.y*q2.y + x2.z*q2.z + x2.w*q2.w
                    + x3.x*q3.x + x3.y*q3.y + x3.z*q3.z + x3.w*q3.w;
            e += __shfl_xor(e, 1); e += __shfl_xor(e, 2);
            e += __shfl_xor(e, 4); e += __shfl_xor(e, 8);
            float w = (qd == 0) ? 1.0f : __expf(e - C);
            if (qd == 0) C = e;
            sacc += w;
            r0.x += w*x0.x; r0.y += w*x0.y; r0.z += w*x0.z; r0.w += w*x0.w;
            r1.x += w*x1.x; r1.y += w*x1.y; r1.z += w*x1.z; r1.w += w*x1.w;
            r2.x += w*x2.x; r2.y += w*x2.y; r2.z += w*x2.z; r2.w += w*x2.w;
            r3.x += w*x3.x; r3.y += w*x3.y; r3.z += w*x3.z; r3.w += w*x3.w;
        }
        *(float4*)&racc_s[pid][s*4]       = r0;
        *(float4*)&racc_s[pid][64  + s*4] = r1;
        *(float4*)&racc_s[pid][128 + s*4] = r2;
        *(float4*)&racc_s[pid][192 + s*4] = r3;
    }
    if (s == 0) { sw_s[pid] = sacc; cw_s[pid] = C; }
    __syncthreads();

    // ---- stage 3: pivot-reconciled merge of 16 partials, d = t ----
    {
        float Cm = cw_s[0];
        #pragma unroll
        for (int p2 = 1; p2 < 16; ++p2) Cm = fmaxf(Cm, cw_s[p2]);
        float S = 0.0f, r = 0.0f;
        #pragma unroll
        for (int p2 = 0; p2 < 16; ++p2) {
            float f = __expf(cw_s[p2] - Cm);
            S += sw_s[p2] * f;
            r += racc_s[p2][t] * f;
        }
        float rv = r / S;
        if (LAST) {
            outp[ob + 256 + t] = rv;
            if (set && t < 128)
                outp[(size_t)b * 1152 + 1024 + t] = fgp[(size_t)b * 128 + t];
        } else {
            hrb[sb * 512 + 256 + t] = f2bf(rv);
        }
    }
}

extern "C" void kernel_launch(void* const* d_in, const int* in_sizes, int n_in,
                              void* d_out, int out_size, void* d_ws, size_t ws_size,
                              hipStream_t stream) {
    const float* feat_atom   = (const float*)d_in[0];
    const float* feat_bond   = (const float*)d_in[2];
    const float* feat_global = (const float*)d_in[4];
    const float* WihA = (const float*)d_in[5];
    const float* WhhA = (const float*)d_in[6];
    const float* bihA = (const float*)d_in[7];
    const float* bhhA = (const float*)d_in[8];
    const float* WihB = (const float*)d_in[9];
    const float* WhhB = (const float*)d_in[10];
    const float* bihB = (const float*)d_in[11];
    const float* bhhB = (const float*)d_in[12];
    float* out = (float*)d_out;

    // workspace layout (bytes)
    char* ws = (char*)d_ws;
    unsigned short* Wc    = (unsigned short*)(ws + 0);        // 2,097,152
    float*          bsum  = (float*)(ws + 2097152);           // 8,192
    unsigned short* gates = (unsigned short*)(ws + 2105344);  // 4,194,304 (bf16)
    unsigned short* hrb   = (unsigned short*)(ws + 6299648);  // 2,097,152 (bf16)
    float*          cst   = (float*)(ws + 8396800);           // 2,097,152
    unsigned int*   i8A   = (unsigned int*)(ws + 10493952);   // 16,777,216
    unsigned int*   i8B   = (unsigned int*)(ws + 27271168);   // 33,554,432
    float*          scA   = (float*)(ws + 60825600);          // 2,097,152
    float*          scB   = (float*)(ws + 62922752);          // 4,194,304
    const size_t WS_NEED = 62922752 + 4194304;                // 67,117,056
    (void)in_sizes; (void)n_in; (void)out_size;

    bool i8 = (ws_size >= WS_NEED);

    k_cvtprep<<<3072, 256, 0, stream>>>(feat_atom, feat_bond, i8A, i8B, scA, scB,
                                        WihA, WhhA, bihA, bhhA,
                                        WihB, WhhB, bihB, bhhB,
                                        Wc, bsum, i8 ? 1 : 0);
    if (i8) {
        k_attn<1, false><<<2048, 256, 0, stream>>>(feat_atom, feat_bond, i8A, i8B,
                                                   scA, scB, gates, bsum, hrb, cst,
                                                   feat_global, out, 0);
        for (int it = 1; it < 5; ++it) {
            k_gemm<<<512, 256, 0, stream>>>(hrb, Wc, bsum, gates);
            k_attn<1, false><<<2048, 256, 0, stream>>>(feat_atom, feat_bond, i8A, i8B,
                                                       scA, scB, gates, bsum, hrb, cst,
                                                       feat_global, out, it);
        }
        k_gemm<<<512, 256, 0, stream>>>(hrb, Wc, bsum, gates);
        k_attn<1, true><<<2048, 256, 0, stream>>>(feat_atom, feat_bond, i8A, i8B,
                                                  scA, scB, gates, bsum, hrb, cst,
                                                  feat_global, out, 5);
    } else {
        k_attn<2, false><<<2048, 256, 0, stream>>>(feat_atom, feat_bond, 0, 0, 0, 0,
                                                   gates, bsum, hrb, cst,
                                                   feat_global, out, 0);
        for (int it = 1; it < 5; ++it) {
            k_gemm<<<512, 256, 0, stream>>>(hrb, Wc, bsum, gates);
            k_attn<2, false><<<2048, 256, 0, stream>>>(feat_atom, feat_bond, 0, 0, 0, 0,
                                                       gates, bsum, hrb, cst,
                                                       feat_global, out, it);
        }
        k_gemm<<<512, 256, 0, stream>>>(hrb, Wc, bsum, gates);
        k_attn<2, true><<<2048, 256, 0, stream>>>(feat_atom, feat_bond, 0, 0, 0, 0,
                                                  gates, bsum, hrb, cst,
                                                  feat_global, out, 5);
    }
}